// Round 3
// baseline (228.814 us; speedup 1.0000x reference)
//
#include <hip/hip_runtime.h>
#include <hip/hip_bf16.h>
#include <stdint.h>

#define T_TOK 8192
#define D_IN  1024
#define N_EXP 8
#define D_OUT 1024

#define BM 128
#define BN 128
#define BK 32

typedef short s8v __attribute__((ext_vector_type(8)));
typedef float f4v __attribute__((ext_vector_type(4)));
typedef unsigned short ushort_t;

__device__ __forceinline__ ushort_t f2bf(float f) {
    uint32_t u = __float_as_uint(f);
    uint32_t r = (u + 0x7fffu + ((u >> 16) & 1u)) >> 16;
    return (ushort_t)r;
}

__device__ __forceinline__ float bf2f(ushort_t u) {
    return __uint_as_float(((uint32_t)u) << 16);
}

__device__ __forceinline__ void async_copy16(const void* g, void* lds) {
    __builtin_amdgcn_global_load_lds(
        (const __attribute__((address_space(1))) unsigned int*)g,
        (__attribute__((address_space(3))) unsigned int*)lds,
        16, 0, 0);
}

#define PIPE_BARRIER_VM0() \
    asm volatile("s_waitcnt vmcnt(0) lgkmcnt(0)\n\ts_barrier" ::: "memory")

// ------- fused prep+route: [0,2048) 4 tokens/block (1 wave/token):
//         x-cast + logits (Wr via LDS) + softmax + top2 + entries;
//         [2048,4096) We transpose.  cnt/psum zeroed by memset before. ------
__global__ __launch_bounds__(256)
void prep_kernel(const float* __restrict__ x,
                 const float* __restrict__ Wr,
                 const float* __restrict__ br,
                 const float* __restrict__ We,
                 ushort_t* __restrict__ xb,
                 ushort_t* __restrict__ Webt,
                 float* __restrict__ wslot,
                 int* __restrict__ entries,
                 int* __restrict__ cnt,
                 float* __restrict__ psum) {
    // union'd LDS: token branch WrL 256 chunks x 33 floats = 33792 B
    //              We branch    tile[64][65] f32            = 16640 B
    __shared__ __attribute__((aligned(16))) char shbuf[33856];
    __shared__ int   lcnt[N_EXP];
    __shared__ int   gbase[N_EXP];
    __shared__ float lps[N_EXP];

    int bid = blockIdx.x;
    int tid = threadIdx.x;

    if (bid < 2048) {
        float* WrL = (float*)shbuf;
        if (tid < N_EXP) { lcnt[tid] = 0; lps[tid] = 0.f; }

        // stage Wr (1024x8 f32 = 32KB) into LDS, chunk q=d/4 at stride 33
        // (reader bank = (lane + const) % 32 -> conflict-free)
#pragma unroll
        for (int m = 0; m < 8; ++m) {
            int g = m * 1024 + tid * 4;                 // coalesced float4
            float4 v = *(const float4*)(Wr + g);
            int q = g >> 5, k = g & 31;
            float* p = WrL + q * 33 + k;
            p[0] = v.x; p[1] = v.y; p[2] = v.z; p[3] = v.w;
        }
        __syncthreads();

        int lane = tid & 63;
        int wv   = tid >> 6;
        int t    = bid * 4 + wv;                        // one token per wave

        // load x (4x float4, coalesced per wave), cast+store bf16, MAC logits
        float acc[N_EXP];
#pragma unroll
        for (int e = 0; e < N_EXP; ++e) acc[e] = 0.f;
#pragma unroll
        for (int j = 0; j < 4; ++j) {
            int d0 = lane * 4 + j * 256;
            float4 xv = *(const float4*)(x + (size_t)t * D_IN + d0);
            ushort4 u;
            u.x = f2bf(xv.x); u.y = f2bf(xv.y);
            u.z = f2bf(xv.z); u.w = f2bf(xv.w);
            *(ushort4*)(xb + (size_t)t * D_IN + d0) = u;
            const float* wr = WrL + (lane + j * 64) * 33;
#pragma unroll
            for (int c = 0; c < 4; ++c) {
                float xj = (c == 0) ? xv.x : (c == 1) ? xv.y : (c == 2) ? xv.z : xv.w;
#pragma unroll
                for (int e = 0; e < N_EXP; ++e)
                    acc[e] += xj * wr[c * 8 + e];
            }
        }
#pragma unroll
        for (int e = 0; e < N_EXP; ++e) {
#pragma unroll
            for (int off = 32; off; off >>= 1)
                acc[e] += __shfl_xor(acc[e], off, 64);
        }

        // per-lane (redundant) softmax + top2; lane 0 commits
        float p[N_EXP];
        float m = acc[0] + br[0];
#pragma unroll
        for (int e = 0; e < N_EXP; ++e) { p[e] = acc[e] + br[e]; }
#pragma unroll
        for (int e = 1; e < N_EXP; ++e) m = fmaxf(m, p[e]);
        float Z = 0.f;
#pragma unroll
        for (int e = 0; e < N_EXP; ++e) { p[e] = expf(p[e] - m); Z += p[e]; }
        float invZ = 1.f / Z;
#pragma unroll
        for (int e = 0; e < N_EXP; ++e) p[e] *= invZ;

        int i0 = 0; float b0 = p[0];
#pragma unroll
        for (int e = 1; e < N_EXP; ++e) if (p[e] > b0) { b0 = p[e]; i0 = e; }
        int i1 = (i0 == 0) ? 1 : 0; float b1 = p[i1];
#pragma unroll
        for (int e = 0; e < N_EXP; ++e)
            if (e != i0 && p[e] > b1) { b1 = p[e]; i1 = e; }

        int lpos0 = 0, lpos1 = 0;
        if (lane == 0) {
            float denom = b0 + b1 + 1e-9f;
            float2 w01; w01.x = b0 / denom; w01.y = b1 / denom;
            *(float2*)(wslot + 2 * t) = w01;
#pragma unroll
            for (int e = 0; e < N_EXP; ++e) atomicAdd(&lps[e], p[e]);
            lpos0 = atomicAdd(&lcnt[i0], 1);
            lpos1 = atomicAdd(&lcnt[i1], 1);
        }
        __syncthreads();
        if (tid < N_EXP) {
            gbase[tid] = atomicAdd(&cnt[tid], lcnt[tid]);
            atomicAdd(&psum[tid], lps[tid]);
        }
        __syncthreads();
        if (lane == 0) {
            entries[i0 * T_TOK + gbase[i0] + lpos0] = 2 * t;
            entries[i1 * T_TOK + gbase[i1] + lpos1] = 2 * t + 1;
        }
    } else {
        float (*tile)[65] = (float(*)[65])shbuf;
        int b  = bid - 2048;           // 0..2047
        int e  = b >> 8;
        int k0 = ((b >> 4) & 15) * 64; // D index
        int h0 = (b & 15) * 64;        // DOUT index

        const float* src = We + ((size_t)e * D_IN + k0) * D_OUT + h0;
#pragma unroll
        for (int it = 0; it < 4; ++it) {
            int lin = it * 256 + tid;
            int r = lin >> 4;
            int c4 = (lin & 15) * 4;
            float4 v = *(const float4*)(src + (size_t)r * D_OUT + c4);
            tile[r][c4]     = v.x; tile[r][c4 + 1] = v.y;
            tile[r][c4 + 2] = v.z; tile[r][c4 + 3] = v.w;
        }
        __syncthreads();
        ushort_t* dst = Webt + ((size_t)e * D_OUT + h0) * D_IN + k0;
#pragma unroll
        for (int it = 0; it < 4; ++it) {
            int lin = it * 256 + tid;
            int h = lin >> 4;
            int k4 = (lin & 15) * 4;
            ushort4 u;
            u.x = f2bf(tile[k4][h]);     u.y = f2bf(tile[k4 + 1][h]);
            u.z = f2bf(tile[k4 + 2][h]); u.w = f2bf(tile[k4 + 3][h]);
            *(ushort4*)(dst + (size_t)h * D_IN + k4) = u;
        }
    }
}

// ------- grouped GEMM, 128x128, 2-slot ring (36KB incl. epilogue alias ->
//         4 blocks/CU, all blocks of an XCD co-resident, 1.0 rounds),
//         m97-style drain pipeline, chunk-XOR swizzle, XCD-pinned experts ----
__global__ __launch_bounds__(256, 4)
void moe_gemm(const ushort_t* __restrict__ xb,
              const ushort_t* __restrict__ Webt,
              const float* __restrict__ be,
              const int* __restrict__ entries,
              const int* __restrict__ cnt,
              const float* __restrict__ wslot,
              ushort_t* __restrict__ yslot) {
    int idx  = blockIdx.x;
    int e    = idx & 7;          // XCD-affinity: expert e -> XCD e
    int rest = idx >> 3;
    int bn   = rest & 7;
    int bm   = rest >> 3;
    int cnte = cnt[e];
    if (bm * BM >= cnte) return;

    // 2 ring slots x (A 8KB + B 8KB) = 32KB; epilogue ot[128][136] = 34.8KB
    __shared__ __attribute__((aligned(16))) char smem[36864];

    int tid    = threadIdx.x;
    int lane   = tid & 63;
    int wv     = tid >> 6;
    int lane15 = lane & 15;
    int quad   = lane >> 4;
    int wm = (wv >> 1) * 64;
    int wn = (wv & 1) * 64;

    // staging addresses (chunk XOR-swizzle to kill LDS read conflicts)
    int rA   = tid >> 2;
    int cper = (tid & 3) ^ ((rA >> 1) & 3);
    const int* epe = entries + e * T_TOK;
    int r0 = bm * BM + rA;
    int r1 = r0 + 64;
    int c0 = r0 < cnte ? r0 : cnte - 1;
    int c1 = r1 < cnte ? r1 : cnte - 1;
    int tok0 = epe[c0] >> 1;
    int tok1 = epe[c1] >> 1;
    const ushort_t* gA0 = xb + (size_t)tok0 * D_IN + cper * 8;
    const ushort_t* gA1 = xb + (size_t)tok1 * D_IN + cper * 8;
    const ushort_t* WB  = Webt + (size_t)e * D_IN * D_OUT + cper * 8;
    const ushort_t* gB0 = WB + (size_t)(bn * BN + rA) * D_IN;
    const ushort_t* gB1 = WB + (size_t)(bn * BN + rA + 64) * D_IN;
    int ldsOff = wv * 1024;

    // fragment read offsets (mirror the XOR swizzle)
    int aoff[4], boff[4];
#pragma unroll
    for (int mi = 0; mi < 4; ++mi) {
        int m = wm + mi * 16 + lane15;
        aoff[mi] = m * 64 + (quad ^ ((m >> 1) & 3)) * 16;
        int n = wn + mi * 16 + lane15;
        boff[mi] = n * 64 + (quad ^ ((n >> 1) & 3)) * 16;
    }

    f4v acc[4][4];
#pragma unroll
    for (int mi = 0; mi < 4; ++mi)
#pragma unroll
        for (int ni = 0; ni < 4; ++ni)
            acc[mi][ni] = (f4v){0.f, 0.f, 0.f, 0.f};

#define STAGE(ti)                                                          \
    do {                                                                   \
        char* _b = smem + ((ti) & 1) * 16384;                              \
        int _k = (ti) * BK;                                                \
        async_copy16(gA0 + _k, _b + ldsOff);                               \
        async_copy16(gA1 + _k, _b + 4096 + ldsOff);                        \
        async_copy16(gB0 + _k, _b + 8192 + ldsOff);                        \
        async_copy16(gB1 + _k, _b + 12288 + ldsOff);                       \
    } while (0)

#define COMPUTE(ti)                                                        \
    do {                                                                   \
        const char* ab = smem + ((ti) & 1) * 16384;                        \
        const char* bb = ab + 8192;                                        \
        s8v a[4], b[4];                                                    \
        _Pragma("unroll")                                                  \
        for (int mi = 0; mi < 4; ++mi) a[mi] = *(const s8v*)(ab + aoff[mi]); \
        _Pragma("unroll")                                                  \
        for (int ni = 0; ni < 4; ++ni) b[ni] = *(const s8v*)(bb + boff[ni]); \
        _Pragma("unroll")                                                  \
        for (int mi = 0; mi < 4; ++mi)                                     \
            _Pragma("unroll")                                              \
            for (int ni = 0; ni < 4; ++ni)                                 \
                acc[mi][ni] = __builtin_amdgcn_mfma_f32_16x16x32_bf16(     \
                    a[mi], b[ni], acc[mi][ni], 0, 0, 0);                   \
    } while (0)

    STAGE(0);
    // drain pipeline: barrier waits stage(i) landed + prior ds_reads done,
    // then stage(i+1) into the freed slot, then compute(i).
#pragma unroll 2
    for (int i = 0; i < 31; ++i) {
        PIPE_BARRIER_VM0();
        STAGE(i + 1);
        COMPUTE(i);
    }
    PIPE_BARRIER_VM0();
    COMPUTE(31);

    // ---- epilogue: scale+bias, stage tile in LDS (aliased), coalesced store
    __syncthreads();   // all ds_reads done before smem is reused as ot
    ushort_t (*ot)[136] = (ushort_t(*)[136])smem;

#pragma unroll
    for (int mi = 0; mi < 4; ++mi) {
#pragma unroll
        for (int r = 0; r < 4; ++r) {
            int lrow = wm + mi * 16 + quad * 4 + r;
            int grow = bm * BM + lrow;
            int cr   = grow < cnte ? grow : cnte - 1;
            float w  = grow < cnte ? wslot[epe[cr]] : 0.f;
#pragma unroll
            for (int ni = 0; ni < 4; ++ni) {
                int lcol = wn + ni * 16 + lane15;
                float bev = be[e * D_OUT + bn * BN + lcol];
                ot[lrow][lcol] = f2bf(w * (acc[mi][ni][r] + bev));
            }
        }
    }
    __syncthreads();

    int row  = tid >> 1;
    int half = tid & 1;
    int grow = bm * BM + row;
    if (grow < cnte) {
        int ent = epe[grow];
        ushort_t* dst = yslot + (size_t)ent * D_OUT + bn * BN + half * 64;
        const ushort_t* srcr = &ot[row][half * 64];
#pragma unroll
        for (int j = 0; j < 8; ++j)
            *(s8v*)(dst + j * 8) = *(const s8v*)(srcr + j * 8);
    }
}

// ------- combine (+ fused aux): y[t] = ys[2t] + ys[2t+1] --------------------
__global__ void combine_kernel(const ushort_t* __restrict__ yslot,
                               const float* __restrict__ psum,
                               const int* __restrict__ cnt,
                               float* __restrict__ out) {
    size_t i = ((size_t)blockIdx.x * 256 + threadIdx.x) * 4;
    size_t t = i >> 10;
    size_t h = i & 1023;
    const ushort_t* p0 = yslot + (2 * t) * D_OUT + h;
    ushort4 a = *(const ushort4*)p0;
    ushort4 b = *(const ushort4*)(p0 + D_OUT);
    float4 o;
    o.x = bf2f(a.x) + bf2f(b.x);
    o.y = bf2f(a.y) + bf2f(b.y);
    o.z = bf2f(a.z) + bf2f(b.z);
    o.w = bf2f(a.w) + bf2f(b.w);
    *(float4*)(out + i) = o;
    if (i == 0) {
        float s = 0.f;
#pragma unroll
        for (int e = 0; e < N_EXP; ++e)
            s += (psum[e] / (float)T_TOK) * ((float)cnt[e] / (float)(T_TOK * 2));
        out[(size_t)T_TOK * D_OUT] = (float)N_EXP * s;
    }
}

extern "C" void kernel_launch(void* const* d_in, const int* in_sizes, int n_in,
                              void* d_out, int out_size, void* d_ws, size_t ws_size,
                              hipStream_t stream) {
    const float* x  = (const float*)d_in[0];
    const float* Wr = (const float*)d_in[1];
    const float* br = (const float*)d_in[2];
    const float* We = (const float*)d_in[3];
    const float* be = (const float*)d_in[4];
    float* out = (float*)d_out;

    char* ws = (char*)d_ws;
    ushort_t* xb      = (ushort_t*)(ws);                    // 16 MiB
    ushort_t* Webt    = (ushort_t*)(ws + 16777216);         // 16 MiB
    ushort_t* yslot   = (ushort_t*)(ws + 33554432);         // 32 MiB (bf16)
    int*      entries = (int*)(ws + 67108864);              // 256 KiB
    float*    wslot   = (float*)(ws + 67371008);            // 64 KiB
    float*    psum    = (float*)(ws + 67698688);            // 32 B
    int*      cnt     = (int*)(ws + 67698720);              // 32 B

    // zero cnt + psum (adjacent, 64 B) before prep's fused routing atomics
    hipMemsetAsync(ws + 67698688, 0, 64, stream);

    hipLaunchKernelGGL(prep_kernel, dim3(4096), dim3(256), 0, stream,
                       x, Wr, br, We, xb, Webt, wslot, entries, cnt, psum);
    hipLaunchKernelGGL(moe_gemm, dim3(4096), dim3(256), 0, stream,
                       xb, Webt, be, entries, cnt, wslot, yslot);
    hipLaunchKernelGGL(combine_kernel, dim3(8192), dim3(256), 0, stream,
                       yslot, psum, cnt, out);
}

// Round 4
// 207.622 us; speedup vs baseline: 1.1021x; 1.1021x over previous
//
#include <hip/hip_runtime.h>
#include <hip/hip_bf16.h>
#include <stdint.h>

#define T_TOK 8192
#define D_IN  1024
#define N_EXP 8
#define D_OUT 1024

#define BM 128
#define BN 128
#define BK 32

typedef short s8v __attribute__((ext_vector_type(8)));
typedef float f4v __attribute__((ext_vector_type(4)));
typedef unsigned short ushort_t;

__device__ __forceinline__ ushort_t f2bf(float f) {
    uint32_t u = __float_as_uint(f);
    uint32_t r = (u + 0x7fffu + ((u >> 16) & 1u)) >> 16;
    return (ushort_t)r;
}

__device__ __forceinline__ float bf2f(ushort_t u) {
    return __uint_as_float(((uint32_t)u) << 16);
}

__device__ __forceinline__ void async_copy16(const void* g, void* lds) {
    __builtin_amdgcn_global_load_lds(
        (const __attribute__((address_space(1))) unsigned int*)g,
        (__attribute__((address_space(3))) unsigned int*)lds,
        16, 0, 0);
}

// phase barriers for the 2-slot counted-vmcnt pipeline
#define VM_BARRIER4() \
    asm volatile("s_waitcnt vmcnt(4)\n\ts_barrier" ::: "memory")
#define VM_BARRIER0() \
    asm volatile("s_waitcnt vmcnt(0)\n\ts_barrier" ::: "memory")
#define LGKM_BARRIER() \
    asm volatile("s_waitcnt lgkmcnt(0)\n\ts_barrier" ::: "memory")

// ------- fused prep: [0,T_TOK) logits+x-cast; [T_TOK,..) We transpose -------
__global__ __launch_bounds__(256)
void prep_kernel(const float* __restrict__ x,
                 const float* __restrict__ Wr,
                 const float* __restrict__ br,
                 const float* __restrict__ We,
                 ushort_t* __restrict__ xb,
                 ushort_t* __restrict__ Webt,
                 float* __restrict__ logits,
                 int* __restrict__ cnt,
                 float* __restrict__ psum) {
    __shared__ float red[4][N_EXP];
    __shared__ float tile[64][65];
    int bid = blockIdx.x;
    int tid = threadIdx.x;

    if (bid < T_TOK) {
        int t    = bid;
        int lane = tid & 63;
        int wv   = tid >> 6;

        float4 xv = *(const float4*)(x + (size_t)t * D_IN + tid * 4);
        ushort4 u;
        u.x = f2bf(xv.x); u.y = f2bf(xv.y);
        u.z = f2bf(xv.z); u.w = f2bf(xv.w);
        *(ushort4*)(xb + (size_t)t * D_IN + tid * 4) = u;

        const float* wr = Wr + (size_t)tid * 4 * N_EXP;
        float acc[N_EXP];
#pragma unroll
        for (int e = 0; e < N_EXP; ++e) acc[e] = 0.f;
#pragma unroll
        for (int j = 0; j < 4; ++j) {
            float xj = (j == 0) ? xv.x : (j == 1) ? xv.y : (j == 2) ? xv.z : xv.w;
#pragma unroll
            for (int e = 0; e < N_EXP; ++e)
                acc[e] += xj * wr[j * N_EXP + e];
        }
#pragma unroll
        for (int e = 0; e < N_EXP; ++e) {
#pragma unroll
            for (int off = 32; off; off >>= 1)
                acc[e] += __shfl_xor(acc[e], off, 64);
        }
        if (lane == 0) {
#pragma unroll
            for (int e = 0; e < N_EXP; ++e) red[wv][e] = acc[e];
        }
        __syncthreads();
        if (tid < N_EXP)
            logits[(size_t)t * N_EXP + tid] =
                red[0][tid] + red[1][tid] + red[2][tid] + red[3][tid] + br[tid];
    } else {
        int b  = bid - T_TOK;          // 0..2047
        int e  = b >> 8;
        int k0 = ((b >> 4) & 15) * 64; // D index
        int h0 = (b & 15) * 64;        // DOUT index
        if (b == 0 && tid < N_EXP) { cnt[tid] = 0; psum[tid] = 0.f; }

        const float* src = We + ((size_t)e * D_IN + k0) * D_OUT + h0;
#pragma unroll
        for (int it = 0; it < 4; ++it) {
            int lin = it * 256 + tid;
            int r = lin >> 4;
            int c4 = (lin & 15) * 4;
            float4 v = *(const float4*)(src + (size_t)r * D_OUT + c4);
            tile[r][c4]     = v.x; tile[r][c4 + 1] = v.y;
            tile[r][c4 + 2] = v.z; tile[r][c4 + 3] = v.w;
        }
        __syncthreads();
        ushort_t* dst = Webt + ((size_t)e * D_OUT + h0) * D_IN + k0;
#pragma unroll
        for (int it = 0; it < 4; ++it) {
            int lin = it * 256 + tid;
            int h = lin >> 4;
            int k4 = (lin & 15) * 4;
            ushort4 u;
            u.x = f2bf(tile[k4][h]);     u.y = f2bf(tile[k4 + 1][h]);
            u.z = f2bf(tile[k4 + 2][h]); u.w = f2bf(tile[k4 + 3][h]);
            *(ushort4*)(dst + (size_t)h * D_IN + k4) = u;
        }
    }
}

// ------- route: softmax + top2 + expert lists (1 token per thread) ----------
__global__ __launch_bounds__(256)
void route_kernel(const float* __restrict__ logits,
                  float* __restrict__ wslot,
                  int* __restrict__ entries,
                  int* __restrict__ cnt,
                  float* __restrict__ psum) {
    __shared__ int lcnt[N_EXP];
    __shared__ int gbase[N_EXP];
    __shared__ float lps[N_EXP];
    int tid  = threadIdx.x;
    int lane = tid & 63;
    int t    = blockIdx.x * 256 + tid;
    if (tid < N_EXP) { lcnt[tid] = 0; lps[tid] = 0.f; }
    __syncthreads();

    float p[N_EXP];
    float4 l0 = *(const float4*)(logits + (size_t)t * N_EXP);
    float4 l1 = *(const float4*)(logits + (size_t)t * N_EXP + 4);
    p[0] = l0.x; p[1] = l0.y; p[2] = l0.z; p[3] = l0.w;
    p[4] = l1.x; p[5] = l1.y; p[6] = l1.z; p[7] = l1.w;

    float m = p[0];
#pragma unroll
    for (int e = 1; e < N_EXP; ++e) m = fmaxf(m, p[e]);
    float Z = 0.f;
#pragma unroll
    for (int e = 0; e < N_EXP; ++e) { p[e] = expf(p[e] - m); Z += p[e]; }
    float invZ = 1.f / Z;
#pragma unroll
    for (int e = 0; e < N_EXP; ++e) p[e] *= invZ;

#pragma unroll
    for (int e = 0; e < N_EXP; ++e) {
        float v = p[e];
#pragma unroll
        for (int off = 32; off; off >>= 1) v += __shfl_xor(v, off, 64);
        if (lane == 0) atomicAdd(&lps[e], v);
    }

    int i0 = 0; float b0 = p[0];
#pragma unroll
    for (int e = 1; e < N_EXP; ++e) if (p[e] > b0) { b0 = p[e]; i0 = e; }
    int i1 = (i0 == 0) ? 1 : 0; float b1 = p[i1];
#pragma unroll
    for (int e = 0; e < N_EXP; ++e)
        if (e != i0 && p[e] > b1) { b1 = p[e]; i1 = e; }
    float denom = b0 + b1 + 1e-9f;
    float2 w01; w01.x = b0 / denom; w01.y = b1 / denom;
    *(float2*)(wslot + 2 * t) = w01;

    int lpos0 = atomicAdd(&lcnt[i0], 1);
    int lpos1 = atomicAdd(&lcnt[i1], 1);
    __syncthreads();
    if (tid < N_EXP) {
        gbase[tid] = atomicAdd(&cnt[tid], lcnt[tid]);
        atomicAdd(&psum[tid], lps[tid]);
    }
    __syncthreads();
    entries[i0 * T_TOK + gbase[i0] + lpos0] = 2 * t;
    entries[i1 * T_TOK + gbase[i1] + lpos1] = 2 * t + 1;
}

// ------- grouped GEMM, 128x128, 2-slot ring + split-barrier counted
//         vmcnt(4) pipeline (never drains in-loop), 36.8KB LDS -> 4
//         blocks/CU (exact 1.0-round packing per XCD), chunk-XOR swizzle,
//         setprio around MFMA (inter-block arbitration), XCD-pinned experts,
//         LDS-staged coalesced bf16 epilogue -------------------------------
__global__ __launch_bounds__(256, 4)
void moe_gemm(const ushort_t* __restrict__ xb,
              const ushort_t* __restrict__ Webt,
              const float* __restrict__ be,
              const int* __restrict__ entries,
              const int* __restrict__ cnt,
              const float* __restrict__ wslot,
              ushort_t* __restrict__ yslot) {
    int idx  = blockIdx.x;
    int e    = idx & 7;          // XCD-affinity: expert e -> XCD e
    int rest = idx >> 3;
    int bn   = rest & 7;
    int bm   = rest >> 3;
    int cnte = cnt[e];
    if (bm * BM >= cnte) return;

    // 2 ring slots x (A 8KB + B 8KB) = 32KB; epilogue ot[128][136] = 34.8KB
    __shared__ __attribute__((aligned(16))) char smem[36864];

    int tid    = threadIdx.x;
    int lane   = tid & 63;
    int wv     = tid >> 6;
    int lane15 = lane & 15;
    int quad   = lane >> 4;
    int wm = (wv >> 1) * 64;
    int wn = (wv & 1) * 64;

    // staging addresses (chunk XOR-swizzle to kill LDS read conflicts)
    int rA   = tid >> 2;
    int cper = (tid & 3) ^ ((rA >> 1) & 3);
    const int* epe = entries + e * T_TOK;
    int r0 = bm * BM + rA;
    int r1 = r0 + 64;
    int c0 = r0 < cnte ? r0 : cnte - 1;
    int c1 = r1 < cnte ? r1 : cnte - 1;
    int tok0 = epe[c0] >> 1;
    int tok1 = epe[c1] >> 1;
    const ushort_t* gA0 = xb + (size_t)tok0 * D_IN + cper * 8;
    const ushort_t* gA1 = xb + (size_t)tok1 * D_IN + cper * 8;
    const ushort_t* WB  = Webt + (size_t)e * D_IN * D_OUT + cper * 8;
    const ushort_t* gB0 = WB + (size_t)(bn * BN + rA) * D_IN;
    const ushort_t* gB1 = WB + (size_t)(bn * BN + rA + 64) * D_IN;
    int ldsOff = wv * 1024;

    // fragment read offsets (mirror the XOR swizzle)
    int aoff[4], boff[4];
#pragma unroll
    for (int mi = 0; mi < 4; ++mi) {
        int m = wm + mi * 16 + lane15;
        aoff[mi] = m * 64 + (quad ^ ((m >> 1) & 3)) * 16;
        int n = wn + mi * 16 + lane15;
        boff[mi] = n * 64 + (quad ^ ((n >> 1) & 3)) * 16;
    }

    f4v acc[4][4];
#pragma unroll
    for (int mi = 0; mi < 4; ++mi)
#pragma unroll
        for (int ni = 0; ni < 4; ++ni)
            acc[mi][ni] = (f4v){0.f, 0.f, 0.f, 0.f};

#define STAGE(ti)                                                          \
    do {                                                                   \
        char* _b = smem + ((ti) & 1) * 16384;                              \
        int _k = (ti) * BK;                                                \
        async_copy16(gA0 + _k, _b + ldsOff);                               \
        async_copy16(gA1 + _k, _b + 4096 + ldsOff);                        \
        async_copy16(gB0 + _k, _b + 8192 + ldsOff);                        \
        async_copy16(gB1 + _k, _b + 12288 + ldsOff);                       \
    } while (0)

#define MFMAS()                                                            \
    do {                                                                   \
        __builtin_amdgcn_s_setprio(1);                                     \
        _Pragma("unroll")                                                  \
        for (int mi = 0; mi < 4; ++mi)                                     \
            _Pragma("unroll")                                              \
            for (int ni = 0; ni < 4; ++ni)                                 \
                acc[mi][ni] = __builtin_amdgcn_mfma_f32_16x16x32_bf16(     \
                    a_[mi], b_[ni], acc[mi][ni], 0, 0, 0);                 \
        __builtin_amdgcn_s_setprio(0);                                     \
    } while (0)

    // prologue: tiles 0 and 1 in flight (8 loads/wave outstanding)
    STAGE(0);
    STAGE(1);

    // split-barrier steady state:
    //   B1: vmcnt(4)+barrier  -> tile i landed (tile i+1 stays in flight)
    //   ds_read tile i to regs
    //   B2: lgkmcnt(0)+barrier -> slot i free across all waves
    //   STAGE(i+2) into slot i  (outstanding back to 8; never drains)
    //   16x MFMA under setprio
#pragma unroll 2
    for (int i = 0; i < 30; ++i) {
        VM_BARRIER4();
        const char* ab = smem + (i & 1) * 16384;
        const char* bb = ab + 8192;
        s8v a_[4], b_[4];
#pragma unroll
        for (int mi = 0; mi < 4; ++mi) a_[mi] = *(const s8v*)(ab + aoff[mi]);
#pragma unroll
        for (int ni = 0; ni < 4; ++ni) b_[ni] = *(const s8v*)(bb + boff[ni]);
        LGKM_BARRIER();
        STAGE(i + 2);
        MFMAS();
    }
    {   // i = 30 (no stage; tile 31 remains in flight)
        VM_BARRIER4();
        const char* ab = smem + 0 * 16384;
        const char* bb = ab + 8192;
        s8v a_[4], b_[4];
#pragma unroll
        for (int mi = 0; mi < 4; ++mi) a_[mi] = *(const s8v*)(ab + aoff[mi]);
#pragma unroll
        for (int ni = 0; ni < 4; ++ni) b_[ni] = *(const s8v*)(bb + boff[ni]);
        MFMAS();
    }
    {   // i = 31 (final drain)
        VM_BARRIER0();
        const char* ab = smem + 1 * 16384;
        const char* bb = ab + 8192;
        s8v a_[4], b_[4];
#pragma unroll
        for (int mi = 0; mi < 4; ++mi) a_[mi] = *(const s8v*)(ab + aoff[mi]);
#pragma unroll
        for (int ni = 0; ni < 4; ++ni) b_[ni] = *(const s8v*)(bb + boff[ni]);
        MFMAS();
    }

    // ---- epilogue: scale+bias, stage tile in LDS (aliased), coalesced store
    __syncthreads();   // all ds_reads done before smem is reused as ot
    ushort_t (*ot)[136] = (ushort_t(*)[136])smem;

#pragma unroll
    for (int mi = 0; mi < 4; ++mi) {
#pragma unroll
        for (int r = 0; r < 4; ++r) {
            int lrow = wm + mi * 16 + quad * 4 + r;
            int grow = bm * BM + lrow;
            int cr   = grow < cnte ? grow : cnte - 1;
            float w  = grow < cnte ? wslot[epe[cr]] : 0.f;
#pragma unroll
            for (int ni = 0; ni < 4; ++ni) {
                int lcol = wn + ni * 16 + lane15;
                float bev = be[e * D_OUT + bn * BN + lcol];
                ot[lrow][lcol] = f2bf(w * (acc[mi][ni][r] + bev));
            }
        }
    }
    __syncthreads();

    int row  = tid >> 1;
    int half = tid & 1;
    int grow = bm * BM + row;
    if (grow < cnte) {
        int ent = epe[grow];
        ushort_t* dst = yslot + (size_t)ent * D_OUT + bn * BN + half * 64;
        const ushort_t* srcr = &ot[row][half * 64];
#pragma unroll
        for (int j = 0; j < 8; ++j)
            *(s8v*)(dst + j * 8) = *(const s8v*)(srcr + j * 8);
    }
}

// ------- combine (+ fused aux): y[t] = ys[2t] + ys[2t+1] --------------------
__global__ void combine_kernel(const ushort_t* __restrict__ yslot,
                               const float* __restrict__ psum,
                               const int* __restrict__ cnt,
                               float* __restrict__ out) {
    size_t i = ((size_t)blockIdx.x * 256 + threadIdx.x) * 4;
    size_t t = i >> 10;
    size_t h = i & 1023;
    const ushort_t* p0 = yslot + (2 * t) * D_OUT + h;
    ushort4 a = *(const ushort4*)p0;
    ushort4 b = *(const ushort4*)(p0 + D_OUT);
    float4 o;
    o.x = bf2f(a.x) + bf2f(b.x);
    o.y = bf2f(a.y) + bf2f(b.y);
    o.z = bf2f(a.z) + bf2f(b.z);
    o.w = bf2f(a.w) + bf2f(b.w);
    *(float4*)(out + i) = o;
    if (i == 0) {
        float s = 0.f;
#pragma unroll
        for (int e = 0; e < N_EXP; ++e)
            s += (psum[e] / (float)T_TOK) * ((float)cnt[e] / (float)(T_TOK * 2));
        out[(size_t)T_TOK * D_OUT] = (float)N_EXP * s;
    }
}

extern "C" void kernel_launch(void* const* d_in, const int* in_sizes, int n_in,
                              void* d_out, int out_size, void* d_ws, size_t ws_size,
                              hipStream_t stream) {
    const float* x  = (const float*)d_in[0];
    const float* Wr = (const float*)d_in[1];
    const float* br = (const float*)d_in[2];
    const float* We = (const float*)d_in[3];
    const float* be = (const float*)d_in[4];
    float* out = (float*)d_out;

    char* ws = (char*)d_ws;
    ushort_t* xb      = (ushort_t*)(ws);                    // 16 MiB
    ushort_t* Webt    = (ushort_t*)(ws + 16777216);         // 16 MiB
    ushort_t* yslot   = (ushort_t*)(ws + 33554432);         // 32 MiB (bf16)
    int*      entries = (int*)(ws + 67108864);              // 256 KiB
    float*    wslot   = (float*)(ws + 67371008);            // 64 KiB
    float*    logits  = (float*)(ws + 67436544);            // 256 KiB
    float*    psum    = (float*)(ws + 67698688);            // 32 B
    int*      cnt     = (int*)(ws + 67698720);              // 32 B

    hipLaunchKernelGGL(prep_kernel, dim3(T_TOK + 2048), dim3(256), 0, stream,
                       x, Wr, br, We, xb, Webt, logits, cnt, psum);
    hipLaunchKernelGGL(route_kernel, dim3(32), dim3(256), 0, stream,
                       logits, wslot, entries, cnt, psum);
    hipLaunchKernelGGL(moe_gemm, dim3(4096), dim3(256), 0, stream,
                       xb, Webt, be, entries, cnt, wslot, yslot);
    hipLaunchKernelGGL(combine_kernel, dim3(8192), dim3(256), 0, stream,
                       yslot, psum, cnt, out);
}